// Round 5
// baseline (748.454 us; speedup 1.0000x reference)
//
#include <hip/hip_runtime.h>
#include <hip/hip_fp16.h>

#define BB 16
#define NN 2048
#define PC 256
#define KK 32
#define HWS 1920
#define PT (BB*PC*KK)   // 131072 positions
#define EPSF 1e-5f
#define THR 512
#define NSTC 32          // stats copies (cacheline-disjoint) when d_ws allows

// d_out-resident scratch (d_ws: idxr mirror + spread stats when available).
// Channel map (phys f32 channels, 8192 floats per batch):
//  ch0..63    : final pf1 (written by conv2 staging, fused)
//  ch64..127  : y3 f16-packed (conv3 out, conv4 X); k_rgb overwrites -> rgb1
//  ch128..255 : final pf2 (written by conv3 staging, fused)
//  ch256..258 : idxr / idx / valid        } k_rgb overwrites ch256..383 -> rgb2
//  ch259 (b0) : BN stats (single-copy fallback), 1152 floats
//  ch260..323 : y2 f16-packed (conv2 out, conv3 X)
//  ch324..355 : y1 f16-packed (conv1 out, conv2 X)
//  ch356..363 : featT f16-packed [n][32q] (k_prep out, conv1 X)
//  ch384..639 : final pf4 (conv4b writes normalized f32 directly)
#define CH_IDXR 256
#define CH_IDX  257
#define CH_VAL  258
#define CH_FT   356
#define STATS_OFF ((size_t)259 << 13)

typedef _Float16 f16x8 __attribute__((ext_vector_type(8)));
typedef float    f32x4 __attribute__((ext_vector_type(4)));

__device__ __forceinline__ unsigned packh2(float lo, float hi) {
  unsigned a = (unsigned)__half_as_ushort(__float2half(lo));
  unsigned b = (unsigned)__half_as_ushort(__float2half(hi));
  return a | (b << 16);
}
__device__ __forceinline__ float h2lo(unsigned u) {
  return __half2float(__ushort_as_half((unsigned short)(u & 0xffffu)));
}
__device__ __forceinline__ float h2hi(unsigned u) {
  return __half2float(__ushort_as_half((unsigned short)(u >> 16)));
}

// ------------- feat transpose: [64ch][2048n] f32 -> [n][32q] f16-pairs ------
__global__ __launch_bounds__(256,2) void k_prep(
    const float* __restrict__ feat, float* out)
{
  __shared__ float tile[64][261];
  int tid = threadIdx.x;
  int b = blockIdx.x >> 3, n0 = (blockIdx.x & 7) << 8;
  #pragma unroll 8
  for (int c = 0; c < 64; c++)
    tile[c][tid] = feat[((size_t)b*64 + c)*NN + n0 + tid];
  __syncthreads();
  unsigned* ftw = (unsigned*)out + (((size_t)b*640 + CH_FT)<<13);
  #pragma unroll
  for (int e = tid; e < 256*32; e += 256) {
    int q = e & 31, nl = e >> 5;
    ftw[(size_t)(n0 + nl)*32 + q] = packh2(tile[2*q][nl], tile[2*q+1][nl]);
  }
}

// ---------------- Stage 1: depth-window top-K neighbor query ----------------
// Also zeroes BN stats (single copy + spread copies) and, when WSC, mirrors
// idxr into d_ws so the LDS k_rgb can read it race-free.
template<bool WSC>
__global__ __launch_bounds__(256) void k_idx(
    const float* __restrict__ pc, const float* __restrict__ npc,
    const int* __restrict__ qv1, float* out, int* __restrict__ wsi,
    float* __restrict__ stz)
{
  __shared__ int slots[4][KK];
  int tid = threadIdx.x;
  int bx = blockIdx.x;
  if (bx < 5) {
    int i = bx*256 + tid;
    if (i < 1152) out[STATS_OFF + i] = 0.0f;
  }
  if (stz != nullptr && bx >= 5 && bx < 5 + (NSTC*1152 + 255)/256) {
    int i = (bx - 5)*256 + tid;
    if (i < NSTC*1152) stz[i] = 0.0f;
  }
  int wl = tid >> 6, lane = tid & 63;
  int w = bx*4 + wl;                   // 0..4095 = b*256+p
  int b = w >> 8, p = w & 255;
  if (lane == 0) slots[wl][0] = 0;     // num==0 fallback index
  float zc = npc[(b*3+2)*PC + p];
  const float* pz = pc + ((size_t)b*3+2)*NN;
  int num = 0;
  for (int ci=0; ci<NN/64; ci++) {
    int n = ci*64 + lane;
    bool m = fabsf(pz[n] - zc) < 0.5f;
    unsigned long long mk = __ballot(m);
    if (m) {
      int rank = num + __popcll(mk & ((1ull<<lane)-1ull));
      if (rank < KK) slots[wl][rank] = n;
    }
    num += __popcll(mk);
  }
  __syncthreads();
  if (lane < KK) {
    int nj = (lane < num) ? slots[wl][lane] : slots[wl][0];
    size_t col = (size_t)p*KK + lane;
    int enc = (num > 0) ? qv1[b*NN + nj] : -1;
    ((int*)out)[(((size_t)b*640 + CH_IDX )<<13) + col] = nj;
    ((int*)out)[(((size_t)b*640 + CH_IDXR)<<13) + col] = enc;
    if constexpr (WSC) wsi[(size_t)b*8192 + col] = enc;
  }
  if (lane == 0)
    out[(((size_t)b*640 + CH_VAL)<<13) + (size_t)p*KK] = (num > 0) ? 1.0f : 0.0f;
}

// ---------------- MFMA conv: Y[pos,och] = sum_c X[c,pos] * W[och,c] --------
// 512 threads = 8 waves, geometry WVP=4 x WVO=2 (wave = 32 pos x 64 och):
// halves LDS A-fragment re-reads vs 2x4 (each X byte read by 2 och-columns,
// not 4) -> inner loop becomes MFMA-bound, not LDS-bound. W in registers.
// X double-buffered in LDS across TILES pos-tiles per block.
// XMODE 0: gather via featT.  XMODE 1: f16-packed y + norm+relu on the fly;
//          PFB>=0 also writes staged X x valid to ch PFB.. (fused pf).
// YMODE 1: f16-packed pair write.  YMODE 2: stats only.  YMODE 3: final
//          normalized f32 x valid write (no stats).
// Stats go to stc[bh*1152 + STOUT + ...], bh = blockhash & (nc-1); consumers
// pre-reduce nc copies.
template<int CIN, int CINP, int COUT, int BOCH, int WVP, int WVO, int WFP, int WFO,
         int XMODE, int XBASE, int YMODE, int YBASE, int STIN, int STOUT,
         int SWZ, int QR, int PFB, int TILES>
__global__ __launch_bounds__(THR,4) void k_mfma(
    const float* __restrict__ pc, const float* __restrict__ npc,
    const float* __restrict__ W,
    const float* __restrict__ g, const float* __restrict__ bv,
    const float* __restrict__ go, const float* __restrict__ bo,
    float* __restrict__ stc, int nc, float* out)
{
  constexpr int KC = CINP/32;
  __shared__ __align__(16) _Float16 xs[2][128*QR*2];
  __shared__ float scs[128], shs[128];
  __shared__ float redu[WVP*BOCH*2];
  __shared__ float ost[(YMODE==3) ? 2*BOCH : 1];

  int tid = threadIdx.x;
  int tile0 = blockIdx.x * TILES;      // tiles 0..1023 = b*64 + pt
  int b = tile0 >> 6;                  // same b for all TILES (64 % TILES == 0)
  int och0 = blockIdx.y * BOCH;
  int bh = (blockIdx.x + blockIdx.y*7) & (nc - 1);

  int wv = tid >> 6, lane = tid & 63;
  int wp = wv % WVP, wo = wv / WVP;
  int lr = lane & 15, lg = lane >> 4;
  int prow0 = wp*(WFP*16), orow0 = wo*(WFO*16);

  // ---- W fragments -> registers (L2-hot; B-frag layout == [och][c] rows)
  f16x8 bfr[KC][WFO];
  #pragma unroll
  for (int kc = 0; kc < KC; kc++)
    #pragma unroll
    for (int fo = 0; fo < WFO; fo++) {
      int orow = och0 + orow0 + fo*16 + lr;
      f16x8 tf;
      if constexpr (XMODE == 0) {
        #pragma unroll
        for (int j = 0; j < 8; j++) {
          int c = kc*32 + lg*8 + j;
          int r = (c < 64) ? c + 3 : (c < 67 ? c - 64 : -1);
          tf[j] = (_Float16)((r >= 0) ? W[(size_t)orow*CIN + r] : 0.f);
        }
      } else {
        const float* wr = W + (size_t)orow*CIN + kc*32 + lg*8;
        float4 w0 = *(const float4*)wr;
        float4 w1 = *(const float4*)(wr + 4);
        tf[0]=(_Float16)w0.x; tf[1]=(_Float16)w0.y; tf[2]=(_Float16)w0.z; tf[3]=(_Float16)w0.w;
        tf[4]=(_Float16)w1.x; tf[5]=(_Float16)w1.y; tf[6]=(_Float16)w1.z; tf[7]=(_Float16)w1.w;
      }
      bfr[kc][fo] = tf;
    }

  if constexpr (XMODE == 1) {
    for (int c = tid; c < CIN; c += THR) {
      float s0 = 0.f, s1 = 0.f;
      for (int k = 0; k < nc; k++) {
        s0 += stc[k*1152 + STIN + c];
        s1 += stc[k*1152 + STIN + CIN + c];
      }
      float m   = s0 * (1.0f/PT);
      float var = s1 * (1.0f/PT) - m*m;
      float s = rsqrtf(var + EPSF) * g[c];
      scs[c] = s; shs[c] = bv[c] - m*s;
    }
  }
  if constexpr (YMODE == 3) {
    // pre-reduce this block's output-channel stats into LDS
    for (int i = tid; i < 2*BOCH; i += THR) {
      int gi = STOUT + ((i < BOCH) ? (och0 + i) : (COUT + och0 + (i - BOCH)));
      float s = 0.f;
      for (int k = 0; k < nc; k++) s += stc[k*1152 + gi];
      ost[i] = s;
    }
  }
  __syncthreads();
  float osc_[WFO], osh_[WFO];
  if constexpr (YMODE == 3) {
    #pragma unroll
    for (int fo = 0; fo < WFO; fo++) {
      int oloc = orow0 + fo*16 + lr;
      float m   = ost[oloc]*(1.0f/PT);
      float var = ost[BOCH+oloc]*(1.0f/PT) - m*m;
      float s = rsqrtf(var + EPSF) * go[och0 + oloc];
      osc_[fo] = s; osh_[fo] = bo[och0 + oloc] - m*s;
    }
  }

  // ---- staging of one pos-tile into xs[t&1]
  auto STAGE = [&](int t) {
    int col0t = ((tile0 + t) & 63) << 7;
    unsigned* xw = (unsigned*)xs[t & 1];
    if constexpr (XMODE == 0) {
      int posl = tid & 127;
      int qb0  = tid >> 7;             // 0..3
      int n = ((const int*)out)[(((size_t)b*640 + CH_IDX)<<13) + col0t + posl];
      const unsigned* ftw = (const unsigned*)out + (((size_t)b*640 + CH_FT)<<13);
      int pcol = (col0t + posl) >> 5;
      #pragma unroll
      for (int k = 0; k < 12; k++) {
        int q = qb0 + k*4;             // covers 0..47
        unsigned u;
        if (q < 32) {
          u = ftw[(size_t)n*32 + q];
        } else if (q == 32) {
          float vx = pc[((size_t)b*3+0)*NN + n] - npc[(b*3+0)*PC + pcol];
          float vy = pc[((size_t)b*3+1)*NN + n] - npc[(b*3+1)*PC + pcol];
          u = packh2(vx, vy);
        } else if (q == 33) {
          float vz = pc[((size_t)b*3+2)*NN + n] - npc[(b*3+2)*PC + pcol];
          u = packh2(vz, 0.f);
        } else u = 0u;
        int qs = (((q>>2) ^ ((posl>>2) & SWZ)) << 2) | (q & 3);
        xw[posl*QR + qs] = u;
      }
    } else {
      #pragma unroll
      for (int k = 0; k < CIN/32; k++) {
        int e = tid + k*THR;
        int q = e >> 5, pg = e & 31;
        uint4 u = *(const uint4*)&((const unsigned*)out)[(((size_t)b*640 + XBASE + q)<<13) + col0t + pg*4];
        float s0 = scs[2*q], h0 = shs[2*q], s1 = scs[2*q+1], h1 = shs[2*q+1];
        unsigned uu[4] = {u.x, u.y, u.z, u.w};
        float lo_a[4], hi_a[4];
        #pragma unroll
        for (int j = 0; j < 4; j++) {
          lo_a[j] = fmaxf(fmaf(h2lo(uu[j]), s0, h0), 0.f);
          hi_a[j] = fmaxf(fmaf(h2hi(uu[j]), s1, h1), 0.f);
          int p = pg*4 + j;
          xw[p*QR + ((((q>>2) ^ ((p>>2) & SWZ)) << 2) | (q & 3))] = packh2(lo_a[j], hi_a[j]);
        }
        if constexpr (PFB >= 0) {
          float vv = out[(((size_t)b*640 + CH_VAL)<<13) + col0t + ((pg >> 3) << 5)];
          float4 L  = {lo_a[0]*vv, lo_a[1]*vv, lo_a[2]*vv, lo_a[3]*vv};
          float4 Hh = {hi_a[0]*vv, hi_a[1]*vv, hi_a[2]*vv, hi_a[3]*vv};
          size_t pb = (((size_t)b*640 + PFB + 2*q)<<13) + col0t + pg*4;
          *(float4*)&out[pb]           = L;
          *(float4*)&out[pb + (1<<13)] = Hh;
        }
      }
    }
  };

  STAGE(0);
  __syncthreads();

  float ssum[WFO], ssq[WFO];
  #pragma unroll
  for (int fo = 0; fo < WFO; fo++) { ssum[fo] = 0.f; ssq[fo] = 0.f; }

  #pragma unroll
  for (int t = 0; t < TILES; t++) {
    int col0t = ((tile0 + t) & 63) << 7;
    const _Float16* xb = xs[t & 1];

    f32x4 acc[WFP][WFO];
    const f32x4 zero4 = {0.f, 0.f, 0.f, 0.f};
    #pragma unroll
    for (int fp = 0; fp < WFP; fp++)
      #pragma unroll
      for (int fo = 0; fo < WFO; fo++) acc[fp][fo] = zero4;

    #pragma unroll
    for (int kc = 0; kc < KC; kc++) {
      f16x8 af[WFP];
      #pragma unroll
      for (int fp = 0; fp < WFP; fp++) {
        int row = prow0 + fp*16 + lr;
        int qb = (kc*4 + lg) ^ ((row>>2) & SWZ);
        af[fp] = *(const f16x8*)&xb[row*(QR*2) + qb*8];
      }
      #pragma unroll
      for (int fp = 0; fp < WFP; fp++)
        #pragma unroll
        for (int fo = 0; fo < WFO; fo++)
          acc[fp][fo] = __builtin_amdgcn_mfma_f32_16x16x32_f16(af[fp], bfr[kc][fo], acc[fp][fo], 0, 0, 0);
    }

    // ---- Y write: C/D layout col(lane&15)=och, row((lane>>4)*4+r)=pos
    if constexpr (YMODE == 1) {
      #pragma unroll
      for (int fp = 0; fp < WFP; fp++) {
        int pos = col0t + prow0 + fp*16 + lg*4;
        #pragma unroll
        for (int fo = 0; fo < WFO; fo++) {
          float pr0 = __shfl_xor(acc[fp][fo][0], 1);
          float pr1 = __shfl_xor(acc[fp][fo][1], 1);
          float pr2 = __shfl_xor(acc[fp][fo][2], 1);
          float pr3 = __shfl_xor(acc[fp][fo][3], 1);
          if (!(lane & 1)) {
            uint4 u;
            u.x = packh2(acc[fp][fo][0], pr0); u.y = packh2(acc[fp][fo][1], pr1);
            u.z = packh2(acc[fp][fo][2], pr2); u.w = packh2(acc[fp][fo][3], pr3);
            int qrow = (och0 + orow0 + fo*16 + lr) >> 1;
            *(uint4*)&((unsigned*)out)[(((size_t)b*640 + YBASE + qrow)<<13) + pos] = u;
          }
        }
      }
    } else if constexpr (YMODE == 3) {
      #pragma unroll
      for (int fp = 0; fp < WFP; fp++) {
        int pos = col0t + prow0 + fp*16 + lg*4;
        float v = out[(((size_t)b*640 + CH_VAL)<<13) + (pos & ~31)];
        #pragma unroll
        for (int fo = 0; fo < WFO; fo++) {
          int och = och0 + orow0 + fo*16 + lr;
          f32x4 wvv;
          #pragma unroll
          for (int r = 0; r < 4; r++)
            wvv[r] = fmaxf(fmaf(acc[fp][fo][r], osc_[fo], osh_[fo]), 0.f) * v;
          *(f32x4*)&out[(((size_t)b*640 + YBASE + och)<<13) + pos] = wvv;
        }
      }
    }

    if constexpr (YMODE != 3) {
      #pragma unroll
      for (int fo = 0; fo < WFO; fo++)
        #pragma unroll
        for (int fp = 0; fp < WFP; fp++)
          #pragma unroll
          for (int r = 0; r < 4; r++) {
            float v = acc[fp][fo][r];
            ssum[fo] += v; ssq[fo] += v*v;
          }
    }

    if (t + 1 < TILES) STAGE(t + 1);
    __syncthreads();
  }

  // ---- BN stats: lane-reduce -> shfl over pos-groups -> LDS -> atomics
  if constexpr (YMODE != 3) {
    #pragma unroll
    for (int fo = 0; fo < WFO; fo++) {
      float s = ssum[fo], q2 = ssq[fo];
      s  += __shfl_down(s, 32);  s  += __shfl_down(s, 16);
      q2 += __shfl_down(q2, 32); q2 += __shfl_down(q2, 16);
      if (lane < 16) {
        int oloc = orow0 + fo*16 + lane;
        redu[(wp*BOCH + oloc)*2]     = s;
        redu[(wp*BOCH + oloc)*2 + 1] = q2;
      }
    }
    __syncthreads();
    float* stg = stc + (size_t)bh*1152 + STOUT;
    for (int i = tid; i < BOCH; i += THR) {
      float ss = 0.f, qq = 0.f;
      #pragma unroll
      for (int p = 0; p < WVP; p++) { ss += redu[(p*BOCH + i)*2]; qq += redu[(p*BOCH + i)*2 + 1]; }
      atomicAdd(&stg[och0 + i], ss);
      atomicAdd(&stg[COUT + och0 + i], qq);
    }
  }
}

// ---- rgb gather, LDS-staged (requires idxr mirror in d_ws) ----------------
// Block = (batch, 4-channel group of [img1(64) ++ img2(128)]).
__global__ __launch_bounds__(512) void k_rgb_lds(
    const float* __restrict__ img1, const float* __restrict__ img2,
    const int* __restrict__ wsi, float* out)
{
  __shared__ float ls[4][HWS];
  int tid = threadIdx.x;
  int b = blockIdx.x / 48, gq = blockIdx.x % 48;
  int gc0 = gq * 4;
  for (int e = tid; e < 4*(HWS/4); e += 512) {
    int c = e / (HWS/4), off = e % (HWS/4);
    int gc = gc0 + c;
    const float* src = (gc < 64) ? img1 + ((size_t)b*64 + gc)*HWS
                                 : img2 + ((size_t)b*128 + (gc-64))*HWS;
    *(float4*)&ls[c][off*4] = *(const float4*)&src[off*4];
  }
  __syncthreads();
  const int* idr = wsi + (size_t)b*8192;
  int dch0 = (gc0 < 64) ? 64 + gc0 : 256 + (gc0 - 64);
  for (int pp = tid; pp < 8192; pp += 512) {
    int enc = idr[pp];
    float v = (enc >= 0) ? 1.0f : 0.0f;
    int ir  = (enc >= 0) ? enc : 0;
    #pragma unroll
    for (int c = 0; c < 4; c++)
      out[(((size_t)b*640 + dch0 + c)<<13) + pp] = ls[c][ir] * v;
  }
}

// ---- rgb gather, fallback (per-thread pos column; no d_ws needed) ---------
__global__ __launch_bounds__(256) void k_rgb_fb(
    const float* __restrict__ img1, const float* __restrict__ img2, float* out)
{
  int tid = threadIdx.x;
  int pos = blockIdx.x*256 + tid;
  int b = pos >> 13, rem = pos & 8191;
  int enc = ((const int*)out)[(((size_t)b*640 + CH_IDXR)<<13) + rem];
  float v  = (enc >= 0) ? 1.0f : 0.0f;
  int  ir  = (enc >= 0) ? enc : 0;
  size_t o1 = (((size_t)b*640 + 64)<<13) + rem;
  const float* i1 = img1 + (size_t)b*64*HWS + ir;
  #pragma unroll 8
  for (int c=0;c<64;c++) out[o1 + ((size_t)c<<13)] = i1[(size_t)c*HWS] * v;
  size_t o2 = (((size_t)b*640 + 256)<<13) + rem;
  const float* i2 = img2 + (size_t)b*128*HWS + ir;
  #pragma unroll 8
  for (int c=0;c<128;c++) out[o2 + ((size_t)c<<13)] = i2[(size_t)c*HWS] * v;
}

extern "C" void kernel_launch(void* const* d_in, const int* in_sizes, int n_in,
                              void* d_out, int out_size, void* d_ws, size_t ws_size,
                              hipStream_t stream)
{
  const float* pc   = (const float*)d_in[0];
  const float* feat = (const float*)d_in[1];
  const float* img1 = (const float*)d_in[2];
  const float* img2 = (const float*)d_in[3];
  // d_in[4] = P (unused by reference)
  const int*   qv1  = (const int*)d_in[5];
  const float* npc  = (const float*)d_in[6];
  const float* w1 = (const float*)d_in[7];
  const float* g1 = (const float*)d_in[8];
  const float* b1 = (const float*)d_in[9];
  const float* w2 = (const float*)d_in[10];
  const float* g2 = (const float*)d_in[11];
  const float* b2 = (const float*)d_in[12];
  const float* w3 = (const float*)d_in[13];
  const float* g3 = (const float*)d_in[14];
  const float* b3 = (const float*)d_in[15];
  const float* w4 = (const float*)d_in[16];
  const float* g4 = (const float*)d_in[17];
  const float* b4 = (const float*)d_in[18];
  float* out = (float*)d_out;
  int*  wsi = (int*)d_ws;
  const bool use_ws = (d_ws != nullptr) && (ws_size >= (size_t)BB*8192*4);
  const bool use_st = (d_ws != nullptr) && (ws_size >= (size_t)BB*8192*4 + (size_t)NSTC*1152*4);
  float* stc = use_st ? ((float*)d_ws + BB*8192) : (out + STATS_OFF);
  int    nc  = use_st ? NSTC : 1;

  k_prep <<<128,256,0,stream>>>(feat, out);
  if (use_ws) k_idx<true ><<<1024,256,0,stream>>>(pc, npc, qv1, out, wsi, use_st ? stc : nullptr);
  else        k_idx<false><<<1024,256,0,stream>>>(pc, npc, qv1, out, wsi, use_st ? stc : nullptr);
  // conv1: gather X via featT (perm order) -> y1 f16-packed @ch324; st @0
  k_mfma<67,96,64,64,    4,2,2,2, 0,0,   1,324, 0,0,     0,48, -1,2>
      <<<dim3(512,1),THR,0,stream>>>(pc,npc,w1,g1,b1,g1,b1,stc,nc,out);
  // conv2: X = norm(y1)@324 -> y2 @ch260; fused pf1 -> ch0..63; st @128
  k_mfma<64,64,128,128,  4,2,2,4, 1,324, 1,260, 0,128,   7,36, 0,2>
      <<<dim3(512,1),THR,0,stream>>>(pc,npc,w2,g1,b1,g1,b1,stc,nc,out);
  // conv3: X = norm(y2)@260 -> y3 @ch64; fused pf2 -> ch128..255; st @384
  k_mfma<128,128,128,128,4,2,2,4, 1,260, 1,64,  128,384, 7,68, 128,2>
      <<<dim3(512,1),THR,0,stream>>>(pc,npc,w3,g2,b2,g2,b2,stc,nc,out);
  // conv4a: X = norm(y3)@64; stats of y4 -> @640 (no Y write)
  k_mfma<128,128,256,128,4,2,2,4, 1,64,  2,0,   384,640, 7,68, -1,2>
      <<<dim3(512,2),THR,0,stream>>>(pc,npc,w4,g3,b3,g3,b3,stc,nc,out);
  // conv4b: recompute y4, write pf4 = relu(norm(y4)) x valid -> ch384..639
  k_mfma<128,128,256,128,4,2,2,4, 1,64,  3,384, 384,640, 7,68, -1,2>
      <<<dim3(512,2),THR,0,stream>>>(pc,npc,w4,g3,b3,g4,b4,stc,nc,out);
  // rgb gathers last (overwrite ch64..127 and ch256..383 incl. all scratch)
  if (use_ws) k_rgb_lds<<<768,512,0,stream>>>(img1, img2, wsi, out);
  else        k_rgb_fb <<<512,256,0,stream>>>(img1, img2, out);
}

// Round 6
// 608.270 us; speedup vs baseline: 1.2305x; 1.2305x over previous
//
#include <hip/hip_runtime.h>
#include <hip/hip_fp16.h>

#define BB 16
#define NN 2048
#define PC 256
#define KK 32
#define HWS 1920
#define PT (BB*PC*KK)   // 131072 positions
#define EPSF 1e-5f
#define THR 512
#define NSTC 32          // stats copies (cacheline-disjoint) when d_ws allows

// d_out-resident scratch (d_ws: idxr mirror + spread stats when available).
// Channel map (phys f32 channels, 8192 floats per batch):
//  ch0..63    : final pf1 (written by conv2 staging, fused)
//  ch64..127  : y3 f16-packed (conv3 out, conv4 X); k_rgb overwrites -> rgb1
//  ch128..255 : final pf2 (written by conv3 staging, fused)
//  ch256..258 : idxr / idx / valid        } k_rgb overwrites ch256..383 -> rgb2
//  ch259 (b0) : BN stats (single-copy fallback), 1152 floats
//  ch260..323 : y2 f16-packed (conv2 out, conv3 X)
//  ch324..355 : y1 f16-packed (conv1 out, conv2 X)
//  ch356..363 : featT f16-packed [n][32q] (k_prep out, conv1 X)
//  ch384..639 : final pf4 (conv4b writes normalized f32 directly)
#define CH_IDXR 256
#define CH_IDX  257
#define CH_VAL  258
#define CH_FT   356
#define STATS_OFF ((size_t)259 << 13)

typedef _Float16 f16x8 __attribute__((ext_vector_type(8)));
typedef float    f32x4 __attribute__((ext_vector_type(4)));

__device__ __forceinline__ unsigned packh2(float lo, float hi) {
  unsigned a = (unsigned)__half_as_ushort(__float2half(lo));
  unsigned b = (unsigned)__half_as_ushort(__float2half(hi));
  return a | (b << 16);
}
__device__ __forceinline__ float h2lo(unsigned u) {
  return __half2float(__ushort_as_half((unsigned short)(u & 0xffffu)));
}
__device__ __forceinline__ float h2hi(unsigned u) {
  return __half2float(__ushort_as_half((unsigned short)(u >> 16)));
}

// ------------- feat transpose: [64ch][2048n] f32 -> [n][32q] f16-pairs ------
__global__ __launch_bounds__(256,2) void k_prep(
    const float* __restrict__ feat, float* out)
{
  __shared__ float tile[64][261];
  int tid = threadIdx.x;
  int b = blockIdx.x >> 3, n0 = (blockIdx.x & 7) << 8;
  #pragma unroll 8
  for (int c = 0; c < 64; c++)
    tile[c][tid] = feat[((size_t)b*64 + c)*NN + n0 + tid];
  __syncthreads();
  unsigned* ftw = (unsigned*)out + (((size_t)b*640 + CH_FT)<<13);
  #pragma unroll
  for (int e = tid; e < 256*32; e += 256) {
    int q = e & 31, nl = e >> 5;
    ftw[(size_t)(n0 + nl)*32 + q] = packh2(tile[2*q][nl], tile[2*q+1][nl]);
  }
}

// ---------------- Stage 1: depth-window top-K neighbor query ----------------
// Also zeroes BN stats (single copy + spread copies) and, when WSC, mirrors
// idxr into d_ws so the LDS k_rgb can read it race-free.
template<bool WSC>
__global__ __launch_bounds__(256) void k_idx(
    const float* __restrict__ pc, const float* __restrict__ npc,
    const int* __restrict__ qv1, float* out, int* __restrict__ wsi,
    float* __restrict__ stz)
{
  __shared__ int slots[4][KK];
  int tid = threadIdx.x;
  int bx = blockIdx.x;
  if (bx < 5) {
    int i = bx*256 + tid;
    if (i < 1152) out[STATS_OFF + i] = 0.0f;
  }
  if (stz != nullptr && bx >= 5 && bx < 5 + (NSTC*1152 + 255)/256) {
    int i = (bx - 5)*256 + tid;
    if (i < NSTC*1152) stz[i] = 0.0f;
  }
  int wl = tid >> 6, lane = tid & 63;
  int w = bx*4 + wl;                   // 0..4095 = b*256+p
  int b = w >> 8, p = w & 255;
  if (lane == 0) slots[wl][0] = 0;     // num==0 fallback index
  float zc = npc[(b*3+2)*PC + p];
  const float* pz = pc + ((size_t)b*3+2)*NN;
  int num = 0;
  for (int ci=0; ci<NN/64; ci++) {
    int n = ci*64 + lane;
    bool m = fabsf(pz[n] - zc) < 0.5f;
    unsigned long long mk = __ballot(m);
    if (m) {
      int rank = num + __popcll(mk & ((1ull<<lane)-1ull));
      if (rank < KK) slots[wl][rank] = n;
    }
    num += __popcll(mk);
  }
  __syncthreads();
  if (lane < KK) {
    int nj = (lane < num) ? slots[wl][lane] : slots[wl][0];
    size_t col = (size_t)p*KK + lane;
    int enc = (num > 0) ? qv1[b*NN + nj] : -1;
    ((int*)out)[(((size_t)b*640 + CH_IDX )<<13) + col] = nj;
    ((int*)out)[(((size_t)b*640 + CH_IDXR)<<13) + col] = enc;
    if constexpr (WSC) wsi[(size_t)b*8192 + col] = enc;
  }
  if (lane == 0)
    out[(((size_t)b*640 + CH_VAL)<<13) + (size_t)p*KK] = (num > 0) ? 1.0f : 0.0f;
}

// ---------------- MFMA conv: Y[pos,och] = sum_c X[c,pos] * W[och,c] --------
// 512 threads = 8 waves, geometry WVP=2 x WVO=4 (round-4 verified config:
// bfr <= 32 VGPR, no spills under the launch_bounds(512,4) 128-VGPR cap).
// W in registers; X double-buffered in LDS across TILES pos-tiles per block.
// XMODE 0: gather via featT.  XMODE 1: f16-packed y + norm+relu on the fly;
//          PFB>=0 also writes staged X x valid to ch PFB.. (fused pf).
// YMODE 1: f16-packed pair write.  YMODE 2: stats only.  YMODE 3: final
//          normalized f32 x valid write (no stats).
// Stats spread: atomics go to stc[bh*1152 + ...], bh in [0,nc); consumers
// pre-reduce the nc copies (kills the conv-tail same-cacheline atomic storm).
template<int CIN, int CINP, int COUT, int BOCH, int WVP, int WVO, int WFP, int WFO,
         int XMODE, int XBASE, int YMODE, int YBASE, int STIN, int STOUT,
         int SWZ, int QR, int PFB, int TILES>
__global__ __launch_bounds__(THR,4) void k_mfma(
    const float* __restrict__ pc, const float* __restrict__ npc,
    const float* __restrict__ W,
    const float* __restrict__ g, const float* __restrict__ bv,
    const float* __restrict__ go, const float* __restrict__ bo,
    float* __restrict__ stc, int nc, float* out)
{
  constexpr int KC = CINP/32;
  __shared__ __align__(16) _Float16 xs[2][128*QR*2];
  __shared__ float scs[128], shs[128];
  __shared__ float redu[WVP*BOCH*2];
  __shared__ float ost[(YMODE==3) ? 2*BOCH : 1];

  int tid = threadIdx.x;
  int tile0 = blockIdx.x * TILES;      // tiles 0..1023 = b*64 + pt
  int b = tile0 >> 6;                  // same b for all TILES (64 % TILES == 0)
  int och0 = blockIdx.y * BOCH;
  int bh = (blockIdx.x + blockIdx.y*7) & (nc - 1);

  int wv = tid >> 6, lane = tid & 63;
  int wp = wv % WVP, wo = wv / WVP;
  int lr = lane & 15, lg = lane >> 4;
  int prow0 = wp*(WFP*16), orow0 = wo*(WFO*16);

  // ---- W fragments -> registers (L2-hot; B-frag layout == [och][c] rows)
  f16x8 bfr[KC][WFO];
  #pragma unroll
  for (int kc = 0; kc < KC; kc++)
    #pragma unroll
    for (int fo = 0; fo < WFO; fo++) {
      int orow = och0 + orow0 + fo*16 + lr;
      f16x8 tf;
      if constexpr (XMODE == 0) {
        #pragma unroll
        for (int j = 0; j < 8; j++) {
          int c = kc*32 + lg*8 + j;
          int r = (c < 64) ? c + 3 : (c < 67 ? c - 64 : -1);
          tf[j] = (_Float16)((r >= 0) ? W[(size_t)orow*CIN + r] : 0.f);
        }
      } else {
        const float* wr = W + (size_t)orow*CIN + kc*32 + lg*8;
        float4 w0 = *(const float4*)wr;
        float4 w1 = *(const float4*)(wr + 4);
        tf[0]=(_Float16)w0.x; tf[1]=(_Float16)w0.y; tf[2]=(_Float16)w0.z; tf[3]=(_Float16)w0.w;
        tf[4]=(_Float16)w1.x; tf[5]=(_Float16)w1.y; tf[6]=(_Float16)w1.z; tf[7]=(_Float16)w1.w;
      }
      bfr[kc][fo] = tf;
    }

  if constexpr (XMODE == 1) {
    for (int c = tid; c < CIN; c += THR) {
      float s0 = 0.f, s1 = 0.f;
      for (int k = 0; k < nc; k++) {
        s0 += stc[k*1152 + STIN + c];
        s1 += stc[k*1152 + STIN + CIN + c];
      }
      float m   = s0 * (1.0f/PT);
      float var = s1 * (1.0f/PT) - m*m;
      float s = rsqrtf(var + EPSF) * g[c];
      scs[c] = s; shs[c] = bv[c] - m*s;
    }
  }
  if constexpr (YMODE == 3) {
    // pre-reduce this block's output-channel stats into LDS
    for (int i = tid; i < 2*BOCH; i += THR) {
      int gi = STOUT + ((i < BOCH) ? (och0 + i) : (COUT + och0 + (i - BOCH)));
      float s = 0.f;
      for (int k = 0; k < nc; k++) s += stc[k*1152 + gi];
      ost[i] = s;
    }
  }
  __syncthreads();
  float osc_[WFO], osh_[WFO];
  if constexpr (YMODE == 3) {
    #pragma unroll
    for (int fo = 0; fo < WFO; fo++) {
      int oloc = orow0 + fo*16 + lr;
      float m   = ost[oloc]*(1.0f/PT);
      float var = ost[BOCH+oloc]*(1.0f/PT) - m*m;
      float s = rsqrtf(var + EPSF) * go[och0 + oloc];
      osc_[fo] = s; osh_[fo] = bo[och0 + oloc] - m*s;
    }
  }

  // ---- staging of one pos-tile into xs[t&1]
  auto STAGE = [&](int t) {
    int col0t = ((tile0 + t) & 63) << 7;
    unsigned* xw = (unsigned*)xs[t & 1];
    if constexpr (XMODE == 0) {
      int posl = tid & 127;
      int qb0  = tid >> 7;             // 0..3
      int n = ((const int*)out)[(((size_t)b*640 + CH_IDX)<<13) + col0t + posl];
      const unsigned* ftw = (const unsigned*)out + (((size_t)b*640 + CH_FT)<<13);
      int pcol = (col0t + posl) >> 5;
      #pragma unroll
      for (int k = 0; k < 12; k++) {
        int q = qb0 + k*4;             // covers 0..47
        unsigned u;
        if (q < 32) {
          u = ftw[(size_t)n*32 + q];
        } else if (q == 32) {
          float vx = pc[((size_t)b*3+0)*NN + n] - npc[(b*3+0)*PC + pcol];
          float vy = pc[((size_t)b*3+1)*NN + n] - npc[(b*3+1)*PC + pcol];
          u = packh2(vx, vy);
        } else if (q == 33) {
          float vz = pc[((size_t)b*3+2)*NN + n] - npc[(b*3+2)*PC + pcol];
          u = packh2(vz, 0.f);
        } else u = 0u;
        int qs = (((q>>2) ^ ((posl>>2) & SWZ)) << 2) | (q & 3);
        xw[posl*QR + qs] = u;
      }
    } else {
      #pragma unroll
      for (int k = 0; k < CIN/32; k++) {
        int e = tid + k*THR;
        int q = e >> 5, pg = e & 31;
        uint4 u = *(const uint4*)&((const unsigned*)out)[(((size_t)b*640 + XBASE + q)<<13) + col0t + pg*4];
        float s0 = scs[2*q], h0 = shs[2*q], s1 = scs[2*q+1], h1 = shs[2*q+1];
        unsigned uu[4] = {u.x, u.y, u.z, u.w};
        float lo_a[4], hi_a[4];
        #pragma unroll
        for (int j = 0; j < 4; j++) {
          lo_a[j] = fmaxf(fmaf(h2lo(uu[j]), s0, h0), 0.f);
          hi_a[j] = fmaxf(fmaf(h2hi(uu[j]), s1, h1), 0.f);
          int p = pg*4 + j;
          xw[p*QR + ((((q>>2) ^ ((p>>2) & SWZ)) << 2) | (q & 3))] = packh2(lo_a[j], hi_a[j]);
        }
        if constexpr (PFB >= 0) {
          float vv = out[(((size_t)b*640 + CH_VAL)<<13) + col0t + ((pg >> 3) << 5)];
          float4 L  = {lo_a[0]*vv, lo_a[1]*vv, lo_a[2]*vv, lo_a[3]*vv};
          float4 Hh = {hi_a[0]*vv, hi_a[1]*vv, hi_a[2]*vv, hi_a[3]*vv};
          size_t pb = (((size_t)b*640 + PFB + 2*q)<<13) + col0t + pg*4;
          *(float4*)&out[pb]           = L;
          *(float4*)&out[pb + (1<<13)] = Hh;
        }
      }
    }
  };

  STAGE(0);
  __syncthreads();

  float ssum[WFO], ssq[WFO];
  #pragma unroll
  for (int fo = 0; fo < WFO; fo++) { ssum[fo] = 0.f; ssq[fo] = 0.f; }

  #pragma unroll
  for (int t = 0; t < TILES; t++) {
    int col0t = ((tile0 + t) & 63) << 7;
    const _Float16* xb = xs[t & 1];

    f32x4 acc[WFP][WFO];
    const f32x4 zero4 = {0.f, 0.f, 0.f, 0.f};
    #pragma unroll
    for (int fp = 0; fp < WFP; fp++)
      #pragma unroll
      for (int fo = 0; fo < WFO; fo++) acc[fp][fo] = zero4;

    #pragma unroll
    for (int kc = 0; kc < KC; kc++) {
      f16x8 af[WFP];
      #pragma unroll
      for (int fp = 0; fp < WFP; fp++) {
        int row = prow0 + fp*16 + lr;
        int qb = (kc*4 + lg) ^ ((row>>2) & SWZ);
        af[fp] = *(const f16x8*)&xb[row*(QR*2) + qb*8];
      }
      #pragma unroll
      for (int fp = 0; fp < WFP; fp++)
        #pragma unroll
        for (int fo = 0; fo < WFO; fo++)
          acc[fp][fo] = __builtin_amdgcn_mfma_f32_16x16x32_f16(af[fp], bfr[kc][fo], acc[fp][fo], 0, 0, 0);
    }

    // ---- Y write: C/D layout col(lane&15)=och, row((lane>>4)*4+r)=pos
    if constexpr (YMODE == 1) {
      #pragma unroll
      for (int fp = 0; fp < WFP; fp++) {
        int pos = col0t + prow0 + fp*16 + lg*4;
        #pragma unroll
        for (int fo = 0; fo < WFO; fo++) {
          float pr0 = __shfl_xor(acc[fp][fo][0], 1);
          float pr1 = __shfl_xor(acc[fp][fo][1], 1);
          float pr2 = __shfl_xor(acc[fp][fo][2], 1);
          float pr3 = __shfl_xor(acc[fp][fo][3], 1);
          if (!(lane & 1)) {
            uint4 u;
            u.x = packh2(acc[fp][fo][0], pr0); u.y = packh2(acc[fp][fo][1], pr1);
            u.z = packh2(acc[fp][fo][2], pr2); u.w = packh2(acc[fp][fo][3], pr3);
            int qrow = (och0 + orow0 + fo*16 + lr) >> 1;
            *(uint4*)&((unsigned*)out)[(((size_t)b*640 + YBASE + qrow)<<13) + pos] = u;
          }
        }
      }
    } else if constexpr (YMODE == 3) {
      #pragma unroll
      for (int fp = 0; fp < WFP; fp++) {
        int pos = col0t + prow0 + fp*16 + lg*4;
        float v = out[(((size_t)b*640 + CH_VAL)<<13) + (pos & ~31)];
        #pragma unroll
        for (int fo = 0; fo < WFO; fo++) {
          int och = och0 + orow0 + fo*16 + lr;
          f32x4 wvv;
          #pragma unroll
          for (int r = 0; r < 4; r++)
            wvv[r] = fmaxf(fmaf(acc[fp][fo][r], osc_[fo], osh_[fo]), 0.f) * v;
          *(f32x4*)&out[(((size_t)b*640 + YBASE + och)<<13) + pos] = wvv;
        }
      }
    }

    if constexpr (YMODE != 3) {
      #pragma unroll
      for (int fo = 0; fo < WFO; fo++)
        #pragma unroll
        for (int fp = 0; fp < WFP; fp++)
          #pragma unroll
          for (int r = 0; r < 4; r++) {
            float v = acc[fp][fo][r];
            ssum[fo] += v; ssq[fo] += v*v;
          }
    }

    if (t + 1 < TILES) STAGE(t + 1);
    __syncthreads();
  }

  // ---- BN stats: lane-reduce -> shfl over pos-groups -> LDS -> atomics
  if constexpr (YMODE != 3) {
    #pragma unroll
    for (int fo = 0; fo < WFO; fo++) {
      float s = ssum[fo], q2 = ssq[fo];
      s  += __shfl_down(s, 32);  s  += __shfl_down(s, 16);
      q2 += __shfl_down(q2, 32); q2 += __shfl_down(q2, 16);
      if (lane < 16) {
        int oloc = orow0 + fo*16 + lane;
        redu[(wp*BOCH + oloc)*2]     = s;
        redu[(wp*BOCH + oloc)*2 + 1] = q2;
      }
    }
    __syncthreads();
    float* stg = stc + (size_t)bh*1152 + STOUT;
    for (int i = tid; i < BOCH; i += THR) {
      float ss = 0.f, qq = 0.f;
      #pragma unroll
      for (int p = 0; p < WVP; p++) { ss += redu[(p*BOCH + i)*2]; qq += redu[(p*BOCH + i)*2 + 1]; }
      atomicAdd(&stg[och0 + i], ss);
      atomicAdd(&stg[COUT + och0 + i], qq);
    }
  }
}

// ---- rgb gather, LDS-staged (requires idxr mirror in d_ws) ----------------
// Block = (batch, 4-channel group of [img1(64) ++ img2(128)]).
__global__ __launch_bounds__(512) void k_rgb_lds(
    const float* __restrict__ img1, const float* __restrict__ img2,
    const int* __restrict__ wsi, float* out)
{
  __shared__ float ls[4][HWS];
  int tid = threadIdx.x;
  int b = blockIdx.x / 48, gq = blockIdx.x % 48;
  int gc0 = gq * 4;
  for (int e = tid; e < 4*(HWS/4); e += 512) {
    int c = e / (HWS/4), off = e % (HWS/4);
    int gc = gc0 + c;
    const float* src = (gc < 64) ? img1 + ((size_t)b*64 + gc)*HWS
                                 : img2 + ((size_t)b*128 + (gc-64))*HWS;
    *(float4*)&ls[c][off*4] = *(const float4*)&src[off*4];
  }
  __syncthreads();
  const int* idr = wsi + (size_t)b*8192;
  int dch0 = (gc0 < 64) ? 64 + gc0 : 256 + (gc0 - 64);
  for (int pp = tid; pp < 8192; pp += 512) {
    int enc = idr[pp];
    float v = (enc >= 0) ? 1.0f : 0.0f;
    int ir  = (enc >= 0) ? enc : 0;
    #pragma unroll
    for (int c = 0; c < 4; c++)
      out[(((size_t)b*640 + dch0 + c)<<13) + pp] = ls[c][ir] * v;
  }
}

// ---- rgb gather, fallback (per-thread pos column; no d_ws needed) ---------
__global__ __launch_bounds__(256) void k_rgb_fb(
    const float* __restrict__ img1, const float* __restrict__ img2, float* out)
{
  int tid = threadIdx.x;
  int pos = blockIdx.x*256 + tid;
  int b = pos >> 13, rem = pos & 8191;
  int enc = ((const int*)out)[(((size_t)b*640 + CH_IDXR)<<13) + rem];
  float v  = (enc >= 0) ? 1.0f : 0.0f;
  int  ir  = (enc >= 0) ? enc : 0;
  size_t o1 = (((size_t)b*640 + 64)<<13) + rem;
  const float* i1 = img1 + (size_t)b*64*HWS + ir;
  #pragma unroll 8
  for (int c=0;c<64;c++) out[o1 + ((size_t)c<<13)] = i1[(size_t)c*HWS] * v;
  size_t o2 = (((size_t)b*640 + 256)<<13) + rem;
  const float* i2 = img2 + (size_t)b*128*HWS + ir;
  #pragma unroll 8
  for (int c=0;c<128;c++) out[o2 + ((size_t)c<<13)] = i2[(size_t)c*HWS] * v;
}

extern "C" void kernel_launch(void* const* d_in, const int* in_sizes, int n_in,
                              void* d_out, int out_size, void* d_ws, size_t ws_size,
                              hipStream_t stream)
{
  const float* pc   = (const float*)d_in[0];
  const float* feat = (const float*)d_in[1];
  const float* img1 = (const float*)d_in[2];
  const float* img2 = (const float*)d_in[3];
  // d_in[4] = P (unused by reference)
  const int*   qv1  = (const int*)d_in[5];
  const float* npc  = (const float*)d_in[6];
  const float* w1 = (const float*)d_in[7];
  const float* g1 = (const float*)d_in[8];
  const float* b1 = (const float*)d_in[9];
  const float* w2 = (const float*)d_in[10];
  const float* g2 = (const float*)d_in[11];
  const float* b2 = (const float*)d_in[12];
  const float* w3 = (const float*)d_in[13];
  const float* g3 = (const float*)d_in[14];
  const float* b3 = (const float*)d_in[15];
  const float* w4 = (const float*)d_in[16];
  const float* g4 = (const float*)d_in[17];
  const float* b4 = (const float*)d_in[18];
  float* out = (float*)d_out;
  int*  wsi = (int*)d_ws;
  const bool use_ws = (d_ws != nullptr) && (ws_size >= (size_t)BB*8192*4);
  const bool use_st = (d_ws != nullptr) && (ws_size >= (size_t)BB*8192*4 + (size_t)NSTC*1152*4);
  float* stc = use_st ? ((float*)d_ws + BB*8192) : (out + STATS_OFF);
  int    nc  = use_st ? NSTC : 1;

  k_prep <<<128,256,0,stream>>>(feat, out);
  if (use_ws) k_idx<true ><<<1024,256,0,stream>>>(pc, npc, qv1, out, wsi, use_st ? stc : nullptr);
  else        k_idx<false><<<1024,256,0,stream>>>(pc, npc, qv1, out, wsi, use_st ? stc : nullptr);
  // conv1: gather X via featT (perm order) -> y1 f16-packed @ch324; st @0
  k_mfma<67,96,64,64,    2,4,4,1, 0,0,   1,324, 0,0,     0,48, -1,2>
      <<<dim3(512,1),THR,0,stream>>>(pc,npc,w1,g1,b1,g1,b1,stc,nc,out);
  // conv2: X = norm(y1)@324 -> y2 @ch260; fused pf1 -> ch0..63; st @128
  k_mfma<64,64,128,128,  2,4,4,2, 1,324, 1,260, 0,128,   7,36, 0,2>
      <<<dim3(512,1),THR,0,stream>>>(pc,npc,w2,g1,b1,g1,b1,stc,nc,out);
  // conv3: X = norm(y2)@260 -> y3 @ch64; fused pf2 -> ch128..255; st @384
  k_mfma<128,128,128,128,2,4,4,2, 1,260, 1,64,  128,384, 7,68, 128,2>
      <<<dim3(512,1),THR,0,stream>>>(pc,npc,w3,g2,b2,g2,b2,stc,nc,out);
  // conv4a: X = norm(y3)@64; stats of y4 -> @640 (no Y write)
  k_mfma<128,128,256,128,2,4,4,2, 1,64,  2,0,   384,640, 7,68, -1,2>
      <<<dim3(512,2),THR,0,stream>>>(pc,npc,w4,g3,b3,g3,b3,stc,nc,out);
  // conv4b: recompute y4, write pf4 = relu(norm(y4)) x valid -> ch384..639
  k_mfma<128,128,256,128,2,4,4,2, 1,64,  3,384, 384,640, 7,68, -1,2>
      <<<dim3(512,2),THR,0,stream>>>(pc,npc,w4,g3,b3,g4,b4,stc,nc,out);
  // rgb gathers last (overwrite ch64..127 and ch256..383 incl. all scratch)
  if (use_ws) k_rgb_lds<<<768,512,0,stream>>>(img1, img2, wsi, out);
  else        k_rgb_fb <<<512,256,0,stream>>>(img1, img2, out);
}

// Round 7
// 546.242 us; speedup vs baseline: 1.3702x; 1.1136x over previous
//
#include <hip/hip_runtime.h>
#include <hip/hip_fp16.h>

#define BB 16
#define NN 2048
#define PC 256
#define KK 32
#define HWS 1920
#define PT (BB*PC*KK)   // 131072 positions
#define EPSF 1e-5f
#define THR 512

// d_out-resident scratch (d_ws used only for an idxr mirror when available).
// Channel map (phys f32 channels, 8192 floats per batch):
//  ch0..63    : final pf1 (written by conv2 staging, fused)
//  ch64..127  : y3 f16-packed (conv3 out, conv4 X); k_rgb overwrites -> rgb1
//  ch128..255 : final pf2 (written by conv3 staging, fused)
//  ch256..258 : idxr / idx / valid        } k_rgb overwrites ch256..383 -> rgb2
//  ch259 (b0) : BN stats, 1152 floats     }
//  ch260..323 : y2 f16-packed (conv2 out, conv3 X)
//  ch324..355 : y1 f16-packed (conv1 out, conv2 X)
//  ch356..363 : featT f16-packed [n][32q] (k_prep out, conv1 X)
//  ch384..639 : final pf4 (conv4b writes normalized f32 directly)
#define CH_IDXR 256
#define CH_IDX  257
#define CH_VAL  258
#define CH_FT   356
#define STATS_OFF ((size_t)259 << 13)

typedef _Float16 f16x8 __attribute__((ext_vector_type(8)));
typedef float    f32x4 __attribute__((ext_vector_type(4)));

__device__ __forceinline__ unsigned packh2(float lo, float hi) {
  unsigned a = (unsigned)__half_as_ushort(__float2half(lo));
  unsigned b = (unsigned)__half_as_ushort(__float2half(hi));
  return a | (b << 16);
}
__device__ __forceinline__ float h2lo(unsigned u) {
  return __half2float(__ushort_as_half((unsigned short)(u & 0xffffu)));
}
__device__ __forceinline__ float h2hi(unsigned u) {
  return __half2float(__ushort_as_half((unsigned short)(u >> 16)));
}
// non-temporal store helpers: final-output writes (never re-read on device)
// bypass L2 retention so y1/y2/y3/featT scratch stays L2-hot for conv reads.
__device__ __forceinline__ void nt_store4(float* p, float4 v) {
  __builtin_nontemporal_store(v.x, p);
  __builtin_nontemporal_store(v.y, p+1);
  __builtin_nontemporal_store(v.z, p+2);
  __builtin_nontemporal_store(v.w, p+3);
}
__device__ __forceinline__ void nt_store1(float* p, float v) {
  __builtin_nontemporal_store(v, p);
}

// ------------- feat transpose: [64ch][2048n] f32 -> [n][32q] f16-pairs ------
__global__ __launch_bounds__(256,2) void k_prep(
    const float* __restrict__ feat, float* out)
{
  __shared__ float tile[64][261];
  int tid = threadIdx.x;
  int b = blockIdx.x >> 3, n0 = (blockIdx.x & 7) << 8;
  #pragma unroll 8
  for (int c = 0; c < 64; c++)
    tile[c][tid] = feat[((size_t)b*64 + c)*NN + n0 + tid];
  __syncthreads();
  unsigned* ftw = (unsigned*)out + (((size_t)b*640 + CH_FT)<<13);
  #pragma unroll
  for (int e = tid; e < 256*32; e += 256) {
    int q = e & 31, nl = e >> 5;
    ftw[(size_t)(n0 + nl)*32 + q] = packh2(tile[2*q][nl], tile[2*q+1][nl]);
  }
}

// ---------------- Stage 1: depth-window top-K neighbor query ----------------
// Also zeroes the BN stats accumulators and, when WSC, mirrors idxr to d_ws.
template<bool WSC>
__global__ __launch_bounds__(256) void k_idx(
    const float* __restrict__ pc, const float* __restrict__ npc,
    const int* __restrict__ qv1, float* out, int* __restrict__ wsi)
{
  __shared__ int slots[4][KK];
  int tid = threadIdx.x;
  if (blockIdx.x < 5) {
    int i = blockIdx.x*256 + tid;
    if (i < 1152) out[STATS_OFF + i] = 0.0f;
  }
  int wl = tid >> 6, lane = tid & 63;
  int w = blockIdx.x*4 + wl;           // 0..4095 = b*256+p
  int b = w >> 8, p = w & 255;
  if (lane == 0) slots[wl][0] = 0;     // num==0 fallback index
  float zc = npc[(b*3+2)*PC + p];
  const float* pz = pc + ((size_t)b*3+2)*NN;
  int num = 0;
  for (int ci=0; ci<NN/64; ci++) {
    int n = ci*64 + lane;
    bool m = fabsf(pz[n] - zc) < 0.5f;
    unsigned long long mk = __ballot(m);
    if (m) {
      int rank = num + __popcll(mk & ((1ull<<lane)-1ull));
      if (rank < KK) slots[wl][rank] = n;
    }
    num += __popcll(mk);
  }
  __syncthreads();
  if (lane < KK) {
    int nj = (lane < num) ? slots[wl][lane] : slots[wl][0];
    size_t col = (size_t)p*KK + lane;
    int enc = (num > 0) ? qv1[b*NN + nj] : -1;
    ((int*)out)[(((size_t)b*640 + CH_IDX )<<13) + col] = nj;
    ((int*)out)[(((size_t)b*640 + CH_IDXR)<<13) + col] = enc;
    if constexpr (WSC) wsi[(size_t)b*8192 + col] = enc;
  }
  if (lane == 0)
    out[(((size_t)b*640 + CH_VAL)<<13) + (size_t)p*KK] = (num > 0) ? 1.0f : 0.0f;
}

// ---------------- MFMA conv: Y[pos,och] = sum_c X[c,pos] * W[och,c] --------
// 512 threads = 8 waves, geometry WVP=2 x WVO=4 (round-4 verified config:
// bfr <= 32 VGPR, no spills under the launch_bounds(512,4) 128-VGPR cap).
// W in registers; X double-buffered in LDS across TILES pos-tiles per block.
// XMODE 0: gather via featT.  XMODE 1: f16-packed y + norm+relu on the fly;
//          PFB>=0 also writes staged X x valid to ch PFB.. (fused pf, nt).
// YMODE 1: f16-packed pair write.  YMODE 2: stats only.  YMODE 3: final
//          normalized f32 x valid write (nt; no stats).
template<int CIN, int CINP, int COUT, int BOCH, int WVP, int WVO, int WFP, int WFO,
         int XMODE, int XBASE, int YMODE, int YBASE, int STIN, int STOUT,
         int SWZ, int QR, int PFB, int TILES>
__global__ __launch_bounds__(THR,4) void k_mfma(
    const float* __restrict__ pc, const float* __restrict__ npc,
    const float* __restrict__ W,
    const float* __restrict__ g, const float* __restrict__ bv,
    const float* __restrict__ go, const float* __restrict__ bo,
    float* out)
{
  constexpr int KC = CINP/32;
  __shared__ __align__(16) _Float16 xs[2][128*QR*2];
  __shared__ float scs[128], shs[128];
  __shared__ float redu[WVP*BOCH*2];
  __shared__ float ost[(YMODE==3) ? 2*BOCH : 1];

  int tid = threadIdx.x;
  int tile0 = blockIdx.x * TILES;      // tiles 0..1023 = b*64 + pt
  int b = tile0 >> 6;                  // same b for all TILES (64 % TILES == 0)
  int och0 = blockIdx.y * BOCH;

  int wv = tid >> 6, lane = tid & 63;
  int wp = wv % WVP, wo = wv / WVP;
  int lr = lane & 15, lg = lane >> 4;
  int prow0 = wp*(WFP*16), orow0 = wo*(WFO*16);

  // ---- W fragments -> registers (L2-hot; B-frag layout == [och][c] rows)
  f16x8 bfr[KC][WFO];
  #pragma unroll
  for (int kc = 0; kc < KC; kc++)
    #pragma unroll
    for (int fo = 0; fo < WFO; fo++) {
      int orow = och0 + orow0 + fo*16 + lr;
      f16x8 tf;
      if constexpr (XMODE == 0) {
        #pragma unroll
        for (int j = 0; j < 8; j++) {
          int c = kc*32 + lg*8 + j;
          int r = (c < 64) ? c + 3 : (c < 67 ? c - 64 : -1);
          tf[j] = (_Float16)((r >= 0) ? W[(size_t)orow*CIN + r] : 0.f);
        }
      } else {
        const float* wr = W + (size_t)orow*CIN + kc*32 + lg*8;
        float4 w0 = *(const float4*)wr;
        float4 w1 = *(const float4*)(wr + 4);
        tf[0]=(_Float16)w0.x; tf[1]=(_Float16)w0.y; tf[2]=(_Float16)w0.z; tf[3]=(_Float16)w0.w;
        tf[4]=(_Float16)w1.x; tf[5]=(_Float16)w1.y; tf[6]=(_Float16)w1.z; tf[7]=(_Float16)w1.w;
      }
      bfr[kc][fo] = tf;
    }

  if constexpr (XMODE == 1) {
    const float* stin = out + STATS_OFF + STIN;
    for (int c = tid; c < CIN; c += THR) {
      float m   = stin[c] * (1.0f/PT);
      float var = stin[CIN+c]*(1.0f/PT) - m*m;
      float s = rsqrtf(var + EPSF) * g[c];
      scs[c] = s; shs[c] = bv[c] - m*s;
    }
  }
  if constexpr (YMODE == 3) {
    const float* sto = out + STATS_OFF + STOUT;
    for (int i = tid; i < 2*BOCH; i += THR) {
      int gi = (i < BOCH) ? (och0 + i) : (COUT + och0 + (i - BOCH));
      ost[i] = sto[gi];
    }
  }
  __syncthreads();
  float osc_[WFO], osh_[WFO];
  if constexpr (YMODE == 3) {
    #pragma unroll
    for (int fo = 0; fo < WFO; fo++) {
      int oloc = orow0 + fo*16 + lr;
      float m   = ost[oloc]*(1.0f/PT);
      float var = ost[BOCH+oloc]*(1.0f/PT) - m*m;
      float s = rsqrtf(var + EPSF) * go[och0 + oloc];
      osc_[fo] = s; osh_[fo] = bo[och0 + oloc] - m*s;
    }
  }

  // ---- staging of one pos-tile into xs[t&1]
  auto STAGE = [&](int t) {
    int col0t = ((tile0 + t) & 63) << 7;
    unsigned* xw = (unsigned*)xs[t & 1];
    if constexpr (XMODE == 0) {
      int posl = tid & 127;
      int qb0  = tid >> 7;             // 0..3
      int n = ((const int*)out)[(((size_t)b*640 + CH_IDX)<<13) + col0t + posl];
      const unsigned* ftw = (const unsigned*)out + (((size_t)b*640 + CH_FT)<<13);
      int pcol = (col0t + posl) >> 5;
      #pragma unroll
      for (int k = 0; k < 12; k++) {
        int q = qb0 + k*4;             // covers 0..47
        unsigned u;
        if (q < 32) {
          u = ftw[(size_t)n*32 + q];
        } else if (q == 32) {
          float vx = pc[((size_t)b*3+0)*NN + n] - npc[(b*3+0)*PC + pcol];
          float vy = pc[((size_t)b*3+1)*NN + n] - npc[(b*3+1)*PC + pcol];
          u = packh2(vx, vy);
        } else if (q == 33) {
          float vz = pc[((size_t)b*3+2)*NN + n] - npc[(b*3+2)*PC + pcol];
          u = packh2(vz, 0.f);
        } else u = 0u;
        int qs = (((q>>2) ^ ((posl>>2) & SWZ)) << 2) | (q & 3);
        xw[posl*QR + qs] = u;
      }
    } else {
      #pragma unroll
      for (int k = 0; k < CIN/32; k++) {
        int e = tid + k*THR;
        int q = e >> 5, pg = e & 31;
        uint4 u = *(const uint4*)&((const unsigned*)out)[(((size_t)b*640 + XBASE + q)<<13) + col0t + pg*4];
        float s0 = scs[2*q], h0 = shs[2*q], s1 = scs[2*q+1], h1 = shs[2*q+1];
        unsigned uu[4] = {u.x, u.y, u.z, u.w};
        float lo_a[4], hi_a[4];
        #pragma unroll
        for (int j = 0; j < 4; j++) {
          lo_a[j] = fmaxf(fmaf(h2lo(uu[j]), s0, h0), 0.f);
          hi_a[j] = fmaxf(fmaf(h2hi(uu[j]), s1, h1), 0.f);
          int p = pg*4 + j;
          xw[p*QR + ((((q>>2) ^ ((p>>2) & SWZ)) << 2) | (q & 3))] = packh2(lo_a[j], hi_a[j]);
        }
        if constexpr (PFB >= 0) {
          float vv = out[(((size_t)b*640 + CH_VAL)<<13) + col0t + ((pg >> 3) << 5)];
          float4 L  = {lo_a[0]*vv, lo_a[1]*vv, lo_a[2]*vv, lo_a[3]*vv};
          float4 Hh = {hi_a[0]*vv, hi_a[1]*vv, hi_a[2]*vv, hi_a[3]*vv};
          size_t pb = (((size_t)b*640 + PFB + 2*q)<<13) + col0t + pg*4;
          nt_store4(&out[pb],           L);
          nt_store4(&out[pb + (1<<13)], Hh);
        }
      }
    }
  };

  STAGE(0);
  __syncthreads();

  float ssum[WFO], ssq[WFO];
  #pragma unroll
  for (int fo = 0; fo < WFO; fo++) { ssum[fo] = 0.f; ssq[fo] = 0.f; }

  #pragma unroll
  for (int t = 0; t < TILES; t++) {
    int col0t = ((tile0 + t) & 63) << 7;
    const _Float16* xb = xs[t & 1];

    f32x4 acc[WFP][WFO];
    const f32x4 zero4 = {0.f, 0.f, 0.f, 0.f};
    #pragma unroll
    for (int fp = 0; fp < WFP; fp++)
      #pragma unroll
      for (int fo = 0; fo < WFO; fo++) acc[fp][fo] = zero4;

    #pragma unroll
    for (int kc = 0; kc < KC; kc++) {
      f16x8 af[WFP];
      #pragma unroll
      for (int fp = 0; fp < WFP; fp++) {
        int row = prow0 + fp*16 + lr;
        int qb = (kc*4 + lg) ^ ((row>>2) & SWZ);
        af[fp] = *(const f16x8*)&xb[row*(QR*2) + qb*8];
      }
      #pragma unroll
      for (int fp = 0; fp < WFP; fp++)
        #pragma unroll
        for (int fo = 0; fo < WFO; fo++)
          acc[fp][fo] = __builtin_amdgcn_mfma_f32_16x16x32_f16(af[fp], bfr[kc][fo], acc[fp][fo], 0, 0, 0);
    }

    // ---- Y write: C/D layout col(lane&15)=och, row((lane>>4)*4+r)=pos
    if constexpr (YMODE == 1) {
      #pragma unroll
      for (int fp = 0; fp < WFP; fp++) {
        int pos = col0t + prow0 + fp*16 + lg*4;
        #pragma unroll
        for (int fo = 0; fo < WFO; fo++) {
          float pr0 = __shfl_xor(acc[fp][fo][0], 1);
          float pr1 = __shfl_xor(acc[fp][fo][1], 1);
          float pr2 = __shfl_xor(acc[fp][fo][2], 1);
          float pr3 = __shfl_xor(acc[fp][fo][3], 1);
          if (!(lane & 1)) {
            uint4 u;
            u.x = packh2(acc[fp][fo][0], pr0); u.y = packh2(acc[fp][fo][1], pr1);
            u.z = packh2(acc[fp][fo][2], pr2); u.w = packh2(acc[fp][fo][3], pr3);
            int qrow = (och0 + orow0 + fo*16 + lr) >> 1;
            *(uint4*)&((unsigned*)out)[(((size_t)b*640 + YBASE + qrow)<<13) + pos] = u;
          }
        }
      }
    } else if constexpr (YMODE == 3) {
      #pragma unroll
      for (int fp = 0; fp < WFP; fp++) {
        int pos = col0t + prow0 + fp*16 + lg*4;
        float v = out[(((size_t)b*640 + CH_VAL)<<13) + (pos & ~31)];
        #pragma unroll
        for (int fo = 0; fo < WFO; fo++) {
          int och = och0 + orow0 + fo*16 + lr;
          float4 wvv;
          wvv.x = fmaxf(fmaf(acc[fp][fo][0], osc_[fo], osh_[fo]), 0.f) * v;
          wvv.y = fmaxf(fmaf(acc[fp][fo][1], osc_[fo], osh_[fo]), 0.f) * v;
          wvv.z = fmaxf(fmaf(acc[fp][fo][2], osc_[fo], osh_[fo]), 0.f) * v;
          wvv.w = fmaxf(fmaf(acc[fp][fo][3], osc_[fo], osh_[fo]), 0.f) * v;
          nt_store4(&out[(((size_t)b*640 + YBASE + och)<<13) + pos], wvv);
        }
      }
    }

    if constexpr (YMODE != 3) {
      #pragma unroll
      for (int fo = 0; fo < WFO; fo++)
        #pragma unroll
        for (int fp = 0; fp < WFP; fp++)
          #pragma unroll
          for (int r = 0; r < 4; r++) {
            float v = acc[fp][fo][r];
            ssum[fo] += v; ssq[fo] += v*v;
          }
    }

    if (t + 1 < TILES) STAGE(t + 1);
    __syncthreads();
  }

  // ---- BN stats: lane-reduce -> shfl over pos-groups -> LDS -> atomics
  if constexpr (YMODE != 3) {
    #pragma unroll
    for (int fo = 0; fo < WFO; fo++) {
      float s = ssum[fo], q2 = ssq[fo];
      s  += __shfl_down(s, 32);  s  += __shfl_down(s, 16);
      q2 += __shfl_down(q2, 32); q2 += __shfl_down(q2, 16);
      if (lane < 16) {
        int oloc = orow0 + fo*16 + lane;
        redu[(wp*BOCH + oloc)*2]     = s;
        redu[(wp*BOCH + oloc)*2 + 1] = q2;
      }
    }
    __syncthreads();
    float* stg = out + STATS_OFF + STOUT;
    for (int i = tid; i < BOCH; i += THR) {
      float ss = 0.f, qq = 0.f;
      #pragma unroll
      for (int p = 0; p < WVP; p++) { ss += redu[(p*BOCH + i)*2]; qq += redu[(p*BOCH + i)*2 + 1]; }
      atomicAdd(&stg[och0 + i], ss);
      atomicAdd(&stg[COUT + och0 + i], qq);
    }
  }
}

// ---- rgb gather, LDS-staged (requires idxr mirror in d_ws) ----------------
// Block = (batch, 4-channel group of [img1(64) ++ img2(128)]).
__global__ __launch_bounds__(512) void k_rgb_lds(
    const float* __restrict__ img1, const float* __restrict__ img2,
    const int* __restrict__ wsi, float* out)
{
  __shared__ float ls[4][HWS];
  int tid = threadIdx.x;
  int b = blockIdx.x / 48, gq = blockIdx.x % 48;
  int gc0 = gq * 4;
  for (int e = tid; e < 4*(HWS/4); e += 512) {
    int c = e / (HWS/4), off = e % (HWS/4);
    int gc = gc0 + c;
    const float* src = (gc < 64) ? img1 + ((size_t)b*64 + gc)*HWS
                                 : img2 + ((size_t)b*128 + (gc-64))*HWS;
    *(float4*)&ls[c][off*4] = *(const float4*)&src[off*4];
  }
  __syncthreads();
  const int* idr = wsi + (size_t)b*8192;
  int dch0 = (gc0 < 64) ? 64 + gc0 : 256 + (gc0 - 64);
  for (int pp = tid; pp < 8192; pp += 512) {
    int enc = idr[pp];
    float v = (enc >= 0) ? 1.0f : 0.0f;
    int ir  = (enc >= 0) ? enc : 0;
    #pragma unroll
    for (int c = 0; c < 4; c++)
      nt_store1(&out[(((size_t)b*640 + dch0 + c)<<13) + pp], ls[c][ir] * v);
  }
}

// ---- rgb gather, fallback (per-thread pos column; no d_ws needed) ---------
__global__ __launch_bounds__(256) void k_rgb_fb(
    const float* __restrict__ img1, const float* __restrict__ img2, float* out)
{
  int tid = threadIdx.x;
  int pos = blockIdx.x*256 + tid;
  int b = pos >> 13, rem = pos & 8191;
  int enc = ((const int*)out)[(((size_t)b*640 + CH_IDXR)<<13) + rem];
  float v  = (enc >= 0) ? 1.0f : 0.0f;
  int  ir  = (enc >= 0) ? enc : 0;
  size_t o1 = (((size_t)b*640 + 64)<<13) + rem;
  const float* i1 = img1 + (size_t)b*64*HWS + ir;
  #pragma unroll 8
  for (int c=0;c<64;c++) out[o1 + ((size_t)c<<13)] = i1[(size_t)c*HWS] * v;
  size_t o2 = (((size_t)b*640 + 256)<<13) + rem;
  const float* i2 = img2 + (size_t)b*128*HWS + ir;
  #pragma unroll 8
  for (int c=0;c<128;c++) out[o2 + ((size_t)c<<13)] = i2[(size_t)c*HWS] * v;
}

extern "C" void kernel_launch(void* const* d_in, const int* in_sizes, int n_in,
                              void* d_out, int out_size, void* d_ws, size_t ws_size,
                              hipStream_t stream)
{
  const float* pc   = (const float*)d_in[0];
  const float* feat = (const float*)d_in[1];
  const float* img1 = (const float*)d_in[2];
  const float* img2 = (const float*)d_in[3];
  // d_in[4] = P (unused by reference)
  const int*   qv1  = (const int*)d_in[5];
  const float* npc  = (const float*)d_in[6];
  const float* w1 = (const float*)d_in[7];
  const float* g1 = (const float*)d_in[8];
  const float* b1 = (const float*)d_in[9];
  const float* w2 = (const float*)d_in[10];
  const float* g2 = (const float*)d_in[11];
  const float* b2 = (const float*)d_in[12];
  const float* w3 = (const float*)d_in[13];
  const float* g3 = (const float*)d_in[14];
  const float* b3 = (const float*)d_in[15];
  const float* w4 = (const float*)d_in[16];
  const float* g4 = (const float*)d_in[17];
  const float* b4 = (const float*)d_in[18];
  float* out = (float*)d_out;
  int*  wsi = (int*)d_ws;
  const bool use_ws = (d_ws != nullptr) && (ws_size >= (size_t)BB*8192*4);

  k_prep <<<128,256,0,stream>>>(feat, out);
  if (use_ws) k_idx<true ><<<1024,256,0,stream>>>(pc, npc, qv1, out, wsi);
  else        k_idx<false><<<1024,256,0,stream>>>(pc, npc, qv1, out, wsi);
  // conv1: gather X via featT (perm order) -> y1 f16-packed @ch324; st @0
  k_mfma<67,96,64,64,    2,4,4,1, 0,0,   1,324, 0,0,     0,48, -1,2>
      <<<dim3(512,1),THR,0,stream>>>(pc,npc,w1,g1,b1,g1,b1,out);
  // conv2: X = norm(y1)@324 -> y2 @ch260; fused pf1 -> ch0..63; st @128
  k_mfma<64,64,128,128,  2,4,4,2, 1,324, 1,260, 0,128,   7,36, 0,2>
      <<<dim3(512,1),THR,0,stream>>>(pc,npc,w2,g1,b1,g1,b1,out);
  // conv3: X = norm(y2)@260 -> y3 @ch64; fused pf2 -> ch128..255; st @384
  k_mfma<128,128,128,128,2,4,4,2, 1,260, 1,64,  128,384, 7,68, 128,2>
      <<<dim3(512,1),THR,0,stream>>>(pc,npc,w3,g2,b2,g2,b2,out);
  // conv4a: X = norm(y3)@64; stats of y4 -> @640 (no Y write)
  k_mfma<128,128,256,128,2,4,4,2, 1,64,  2,0,   384,640, 7,68, -1,2>
      <<<dim3(512,2),THR,0,stream>>>(pc,npc,w4,g3,b3,g3,b3,out);
  // conv4b: recompute y4, write pf4 = relu(norm(y4)) x valid -> ch384..639
  k_mfma<128,128,256,128,2,4,4,2, 1,64,  3,384, 384,640, 7,68, -1,2>
      <<<dim3(512,2),THR,0,stream>>>(pc,npc,w4,g3,b3,g4,b4,out);
  // rgb gathers last (overwrite ch64..127 and ch256..383 incl. all scratch)
  if (use_ws) k_rgb_lds<<<768,512,0,stream>>>(img1, img2, wsi, out);
  else        k_rgb_fb <<<512,256,0,stream>>>(img1, img2, out);
}